// Round 3
// baseline (281.110 us; speedup 1.0000x reference)
//
#include <hip/hip_runtime.h>
#include <stdint.h>

typedef __bf16 bf16x8 __attribute__((ext_vector_type(8)));
typedef short  short4v __attribute__((ext_vector_type(4)));   // 4 x bf16 bits
typedef float  floatx4 __attribute__((ext_vector_type(4)));

#define DI __device__ __forceinline__

DI float bf2f(uint16_t u) {
    union { uint32_t i; float f; } v; v.i = ((uint32_t)u) << 16; return v.f;
}
DI uint16_t f2bf(float f) {
    union { float f; uint32_t i; } v; v.f = f;
    uint32_t u = v.i;
    return (uint16_t)((u + 0x7FFFu + ((u >> 16) & 1u)) >> 16);  // RNE
}

// ---------------------------------------------------------------------------
// Kernel 0: dtype detector (fp32 vs bf16 inputs). See round-1 notes.
// ---------------------------------------------------------------------------
__global__ __launch_bounds__(64) void detect_kernel(
    const uint32_t* __restrict__ x, int* __restrict__ flag)
{
    int lane = threadIdx.x;
    int cnt = 0;
#pragma unroll
    for (int i = 0; i < 4; i++) {
        uint32_t w = x[lane * 4 + i];
        uint32_t e = (w >> 23) & 0xFF;
        if (e >= 64 && e <= 192) cnt++;
    }
    for (int m = 1; m < 64; m <<= 1) cnt += __shfl_xor(cnt, m);
    if (lane == 0) *flag = (cnt >= 240) ? 1 : 0;   // 1 = fp32 inputs
}

// ---------------------------------------------------------------------------
// Kernel 1: projections. th stores theta-proj PRE-SCALED by log2(e) so the
// flash kernel can use raw v_exp_f32 (exp2).
//   th [blk][4096][32] bf16   phT [blk][4096][32]   gxT [blk][32][4096]
// ---------------------------------------------------------------------------
__global__ __launch_bounds__(256) void proj_kernel(
    const void* __restrict__ x,
    const void* __restrict__ theta_w, const void* __restrict__ theta_b,
    const void* __restrict__ phi_w,   const void* __restrict__ phi_b,
    const void* __restrict__ g_w,     const void* __restrict__ g_b,
    const int* __restrict__ flag,
    uint16_t* __restrict__ th, uint16_t* __restrict__ phT,
    uint16_t* __restrict__ gxT)
{
    int wgid  = blockIdx.x;
    int chunk = wgid % 6;            // wg-uniform
    int ntile = (wgid / 6) % 16;
    int blk   = wgid / 96;
    int p  = chunk >> 1;
    int o0 = (chunk & 1) * 16;
    int n  = ntile * 256 + threadIdx.x;
    int b = blk & 1, q = blk >> 1, qh = q >> 1, qw = q & 1;
    int i = n >> 6, j = n & 63;
    size_t xoff = (size_t)b * 1048576 + (size_t)(qh * 64 + i) * 128 + qw * 64 + j;

    const void* W  = (p == 0) ? theta_w : (p == 1) ? phi_w : g_w;
    const void* Bv = (p == 0) ? theta_b : (p == 1) ? phi_b : g_b;

    float acc[16];
    if (*flag) {                                   // fp32 inputs
        const float* Wf = (const float*)W;
        const float* Bf = (const float*)Bv;
        const float* xf = (const float*)x + xoff;
#pragma unroll
        for (int k = 0; k < 16; k++) acc[k] = Bf[o0 + k];
        for (int c = 0; c < 64; c++) {
            float xv = xf[(size_t)c * 16384];
#pragma unroll
            for (int k = 0; k < 16; k++)
                acc[k] += Wf[(o0 + k) * 64 + c] * xv;
        }
    } else {                                       // bf16 inputs
        const uint16_t* Wh = (const uint16_t*)W;
        const uint16_t* Bh = (const uint16_t*)Bv;
        const uint16_t* xh = (const uint16_t*)x + xoff;
#pragma unroll
        for (int k = 0; k < 16; k++) acc[k] = bf2f(Bh[o0 + k]);
        for (int c = 0; c < 64; c++) {
            float xv = bf2f(xh[(size_t)c * 16384]);
#pragma unroll
            for (int k = 0; k < 16; k++)
                acc[k] += bf2f(Wh[(o0 + k) * 64 + c]) * xv;
        }
    }

    if (p < 2) {
        if (p == 0) {
#pragma unroll
            for (int k = 0; k < 16; k++) acc[k] *= 1.44269504088896f;  // log2(e)
        }
        uint16_t* dst = (p == 0 ? th : phT) + ((size_t)blk * 4096 + n) * 32 + o0;
#pragma unroll
        for (int k = 0; k < 16; k += 2) {
            uint32_t v = (uint32_t)f2bf(acc[k]) | ((uint32_t)f2bf(acc[k + 1]) << 16);
            *(uint32_t*)(dst + k) = v;
        }
    } else {
        uint16_t* dst = gxT + (size_t)blk * 131072 + n;
#pragma unroll
        for (int k = 0; k < 16; k++) dst[(size_t)(o0 + k) * 4096] = f2bf(acc[k]);
    }
}

// ---------------------------------------------------------------------------
// Kernel 2: fused attention, S-transposed formulation, no LDS, 4-way split-K.
//   S^T = mfma_16x16x32(A=K, B=Q)  -> C rows = keys (quad*4+r), cols = query.
//   P (exp2, bf16-packed via v_perm) is DIRECTLY the B operand of
//   mfma_f32_16x16x16_bf16 (k = quad*4+j).  A operand = V^T 8B loads.
// Partial (unnormalized) output + row-sums accumulated with atomicAdd.
// grid: blk(8) x rt(64) x kc(4) = 2048 WGs of 4 waves.
// ---------------------------------------------------------------------------
__global__ __launch_bounds__(256, 6) void flash_kernel(
    const uint16_t* __restrict__ th, const uint16_t* __restrict__ phT,
    const uint16_t* __restrict__ gxT, float* __restrict__ yT,
    float* __restrict__ lsum)
{
    int kc  = blockIdx.x & 3;
    int rt  = (blockIdx.x >> 2) & 63;
    int blk = blockIdx.x >> 8;
    int tid = threadIdx.x;
    int wid = tid >> 6, lane = tid & 63;
    int quad = lane >> 4, low = lane & 15;
    int n0 = rt * 64 + wid * 16;

    const uint16_t* thB = th  + (size_t)blk * 131072;
    const uint16_t* phB = phT + (size_t)blk * 131072;
    const uint16_t* gxB = gxT + (size_t)blk * 131072;

    // Q fragment (B operand of QK): th[n0+low][quad*8 .. +7], log2e-scaled
    bf16x8 qf = *(const bf16x8*)(thB + (n0 + low) * 32 + quad * 8);

    floatx4 zero = {0.f, 0.f, 0.f, 0.f};
    floatx4 oacc0 = zero, oacc1 = zero;
    float psum = 0.f;

    const uint16_t* vrow0 = gxB + (size_t)( 0 + low) * 4096 + quad * 4;
    const uint16_t* vrow1 = gxB + (size_t)(16 + low) * 4096 + quad * 4;

    for (int mt = kc * 16; mt < kc * 16 + 16; ++mt) {
        int m0 = mt * 64;
        // K fragments (A operand): rows = keys m0+c*16+low, chans quad*8..+7
        bf16x8 kf0 = *(const bf16x8*)(phB + (m0 +  0 + low) * 32 + quad * 8);
        bf16x8 kf1 = *(const bf16x8*)(phB + (m0 + 16 + low) * 32 + quad * 8);
        bf16x8 kf2 = *(const bf16x8*)(phB + (m0 + 32 + low) * 32 + quad * 8);
        bf16x8 kf3 = *(const bf16x8*)(phB + (m0 + 48 + low) * 32 + quad * 8);
        // V^T fragments (A operand of PV): row o, cols m0+c*16+quad*4 ..+3
        short4v vf0[4], vf1[4];
#pragma unroll
        for (int c = 0; c < 4; c++) {
            vf0[c] = *(const short4v*)(vrow0 + m0 + c * 16);
            vf1[c] = *(const short4v*)(vrow1 + m0 + c * 16);
        }
        bf16x8 kf[4] = {kf0, kf1, kf2, kf3};
#pragma unroll
        for (int c = 0; c < 4; c++) {
            floatx4 sa = __builtin_amdgcn_mfma_f32_16x16x32_bf16(kf[c], qf, zero, 0, 0, 0);
            // P^T[key=quad*4+r][query=low]
            float p0 = __builtin_amdgcn_exp2f(sa[0]);
            float p1 = __builtin_amdgcn_exp2f(sa[1]);
            float p2 = __builtin_amdgcn_exp2f(sa[2]);
            float p3 = __builtin_amdgcn_exp2f(sa[3]);
            psum += (p0 + p1) + (p2 + p3);
            uint32_t b0 = __float_as_uint(p0) + 0x8000u;
            uint32_t b1 = __float_as_uint(p1) + 0x8000u;
            uint32_t b2 = __float_as_uint(p2) + 0x8000u;
            uint32_t b3 = __float_as_uint(p3) + 0x8000u;
            union { uint32_t u[2]; short4v v; } P;
            P.u[0] = __builtin_amdgcn_perm(b1, b0, 0x07060302u);  // [p0,p1] bf16
            P.u[1] = __builtin_amdgcn_perm(b3, b2, 0x07060302u);  // [p2,p3]
            oacc0 = __builtin_amdgcn_mfma_f32_16x16x16bf16_1k(vf0[c], P.v, oacc0, 0, 0, 0);
            oacc1 = __builtin_amdgcn_mfma_f32_16x16x16bf16_1k(vf1[c], P.v, oacc1, 0, 0, 0);
        }
    }

    // per-query row sum: reduce over the 4 quads
    psum += __shfl_xor(psum, 16);
    psum += __shfl_xor(psum, 32);

    float* yB = yT + (size_t)blk * 131072;
#pragma unroll
    for (int r = 0; r < 4; r++) {
        atomicAdd(yB + (size_t)( 0 + quad * 4 + r) * 4096 + n0 + low, oacc0[r]);
        atomicAdd(yB + (size_t)(16 + quad * 4 + r) * 4096 + n0 + low, oacc1[r]);
    }
    if (quad == 0)
        atomicAdd(lsum + blk * 4096 + n0 + low, psum);
}

// ---------------------------------------------------------------------------
// Kernel 3: normalize + W-projection.
//   wy[blk][c][n] = sum_o w_w[c][o] * (yT[blk][o][n]/lsum[blk][n]) + w_b[c]
// ---------------------------------------------------------------------------
__global__ __launch_bounds__(256) void wy_kernel(
    const float* __restrict__ yT, const float* __restrict__ lsum,
    const void* __restrict__ w_w, const void* __restrict__ w_b,
    const int* __restrict__ flag, float* __restrict__ wy)
{
    int blk = blockIdx.x >> 4, nt = blockIdx.x & 15;
    int n = nt * 256 + threadIdx.x;
    const float* yB = yT + (size_t)blk * 131072 + n;
    float rinv = 1.0f / lsum[blk * 4096 + n];
    float yv[32];
#pragma unroll
    for (int o = 0; o < 32; o++) yv[o] = yB[(size_t)o * 4096] * rinv;
    float* wB = wy + (size_t)blk * 262144 + n;
    if (*flag) {
        const float* wwf = (const float*)w_w;
        const float* wbf = (const float*)w_b;
        for (int c = 0; c < 64; c++) {
            float acc = wbf[c];
#pragma unroll
            for (int o = 0; o < 32; o++) acc += wwf[c * 32 + o] * yv[o];
            wB[(size_t)c * 4096] = acc;
        }
    } else {
        const uint16_t* wwh = (const uint16_t*)w_w;
        const uint16_t* wbh = (const uint16_t*)w_b;
        for (int c = 0; c < 64; c++) {
            float acc = bf2f(wbh[c]);
#pragma unroll
            for (int o = 0; o < 32; o++) acc += bf2f(wwh[c * 32 + o]) * yv[o];
            wB[(size_t)c * 4096] = acc;
        }
    }
}

// ---------------------------------------------------------------------------
// Kernel 4: BN stats per (q,c) -> (scale, shift)
// ---------------------------------------------------------------------------
__global__ __launch_bounds__(256) void stats_kernel(
    const float* __restrict__ wy, const void* __restrict__ gamma,
    const void* __restrict__ beta, const int* __restrict__ flag,
    float2* __restrict__ stats)
{
    int q = blockIdx.x >> 6, c = blockIdx.x & 63;
    int tid = threadIdx.x;
    const float* r0 = wy + ((size_t)(q * 2 + 0) * 64 + c) * 4096;
    const float* r1 = wy + ((size_t)(q * 2 + 1) * 64 + c) * 4096;
    float s = 0.f, ss = 0.f;
    for (int t = tid; t < 4096; t += 256) {
        float a = r0[t], b = r1[t];
        s += a + b; ss += a * a + b * b;
    }
    for (int m = 1; m < 64; m <<= 1) { s += __shfl_xor(s, m); ss += __shfl_xor(ss, m); }
    __shared__ float sh[8];
    int wid = tid >> 6;
    if ((tid & 63) == 0) { sh[wid] = s; sh[4 + wid] = ss; }
    __syncthreads();
    if (tid == 0) {
        float S  = sh[0] + sh[1] + sh[2] + sh[3];
        float SS = sh[4] + sh[5] + sh[6] + sh[7];
        float mu = S * (1.0f / 8192.0f);
        float var = SS * (1.0f / 8192.0f) - mu * mu;
        float gv, bv;
        if (*flag) { gv = ((const float*)gamma)[c]; bv = ((const float*)beta)[c]; }
        else       { gv = bf2f(((const uint16_t*)gamma)[c]); bv = bf2f(((const uint16_t*)beta)[c]); }
        float scale = gv * rsqrtf(var + 1e-5f);
        float shift = bv - mu * scale;
        stats[q * 64 + c] = make_float2(scale, shift);
    }
}

// ---------------------------------------------------------------------------
// Kernel 5: out = (wy * scale + shift) + x, quadrant reassembly.
// ---------------------------------------------------------------------------
__global__ __launch_bounds__(256) void final_kernel(
    const float* __restrict__ wy, const float2* __restrict__ stats,
    const void* __restrict__ x, const int* __restrict__ flag,
    void* __restrict__ out)
{
    size_t idx = (size_t)blockIdx.x * 256 + threadIdx.x;
    int n   = (int)(idx & 4095);
    int c   = (int)((idx >> 12) & 63);
    int blk = (int)(idx >> 18);
    int b = blk & 1, q = blk >> 1, qh = q >> 1, qw = q & 1;
    int i = n >> 6, j = n & 63;
    float2 sc = stats[q * 64 + c];
    float v = wy[idx] * sc.x + sc.y;
    size_t xa = ((size_t)(b * 64 + c) * 128 + (qh * 64 + i)) * 128 + qw * 64 + j;
    if (*flag) {
        ((float*)out)[xa] = v + ((const float*)x)[xa];
    } else {
        ((uint16_t*)out)[xa] = f2bf(v + bf2f(((const uint16_t*)x)[xa]));
    }
}

// ---------------------------------------------------------------------------
extern "C" void kernel_launch(void* const* d_in, const int* in_sizes, int n_in,
                              void* d_out, int out_size, void* d_ws, size_t ws_size,
                              hipStream_t stream)
{
    const void* x       = d_in[0];
    const void* g_w     = d_in[1];
    const void* g_b     = d_in[2];
    const void* theta_w = d_in[3];
    const void* theta_b = d_in[4];
    const void* phi_w   = d_in[5];
    const void* phi_b   = d_in[6];
    const void* w_w     = d_in[7];
    const void* w_b     = d_in[8];
    const void* gamma   = d_in[9];
    const void* beta    = d_in[10];

    char* ws = (char*)d_ws;
    int*      flag  = (int*)(ws);                       // 4 B
    float2*   stats = (float2*)(ws + 1024);             // 2 KB
    uint16_t* th    = (uint16_t*)(ws + (1u  << 20));    // 2 MB
    uint16_t* phT   = (uint16_t*)(ws + (3u  << 20));    // 2 MB
    uint16_t* gxT   = (uint16_t*)(ws + (5u  << 20));    // 2 MB
    float*    yT    = (float*)   (ws + (7u  << 20));    // 4 MB (atomic acc)
    float*    lsum  = (float*)   (ws + (11u << 20));    // 128 KB
    float*    wy    = (float*)   (ws + (12u << 20));    // 8 MB (ends 20 MB)

    detect_kernel<<<1,    64,  0, stream>>>((const uint32_t*)x, flag);
    proj_kernel  <<<768,  256, 0, stream>>>(x, theta_w, theta_b, phi_w, phi_b,
                                            g_w, g_b, flag, th, phT, gxT);
    // zero the atomic accumulators (yT 4 MB + lsum 128 KB, contiguous)
    hipMemsetAsync(yT, 0, (4u << 20) + (128u << 10), stream);
    flash_kernel <<<2048, 256, 0, stream>>>(th, phT, gxT, yT, lsum);
    wy_kernel    <<<128,  256, 0, stream>>>(yT, lsum, w_w, w_b, flag, wy);
    stats_kernel <<<256,  256, 0, stream>>>(wy, gamma, beta, flag, stats);
    final_kernel <<<8192, 256, 0, stream>>>(wy, stats, x, flag, d_out);
}

// Round 4
// 255.415 us; speedup vs baseline: 1.1006x; 1.1006x over previous
//
#include <hip/hip_runtime.h>
#include <stdint.h>

typedef __bf16 bf16x8 __attribute__((ext_vector_type(8)));
typedef short  short4v __attribute__((ext_vector_type(4)));   // 4 x bf16 bits
typedef float  floatx4 __attribute__((ext_vector_type(4)));
typedef uint32_t u32x4 __attribute__((ext_vector_type(4)));

#define DI __device__ __forceinline__

DI uint16_t f2bf(float f) {
    union { float f; uint32_t i; } v; v.f = f;
    uint32_t u = v.i;
    return (uint16_t)((u + 0x7FFFu + ((u >> 16) & 1u)) >> 16);  // RNE
}

// ---------------------------------------------------------------------------
// Kernel 1: projections (fp32 inputs — validated rounds 2/3).
// Grid 8 blk x 64 ntile. WG stages x-tile (64c x 64n fp32, 16KB LDS) once,
// then each thread computes 8 outputs of ALL THREE projections for one n.
//   th [blk][4096][32] bf16 (theta, pre-scaled by log2 e)
//   phT[blk][4096][32] bf16 (phi)
//   vP [blk][tile=n>>6][o=32][k=n&63] bf16 (g, tile-blocked for flash staging)
// WG 0 also zeroes the BN accumulators (used by wy_kernel's atomics).
// ---------------------------------------------------------------------------
__global__ __launch_bounds__(256) void proj_kernel(
    const float* __restrict__ x,
    const float* __restrict__ tw, const float* __restrict__ tb,
    const float* __restrict__ pw, const float* __restrict__ pb,
    const float* __restrict__ gw, const float* __restrict__ gb,
    uint16_t* __restrict__ th, uint16_t* __restrict__ phT,
    uint16_t* __restrict__ vP, float* __restrict__ accum)
{
    int nt = blockIdx.x & 63, blk = blockIdx.x >> 6;
    int tid = threadIdx.x;
    if (blockIdx.x == 0) { accum[tid] = 0.f; accum[256 + tid] = 0.f; }

    __shared__ float xs[64 * 64];
    int b = blk & 1, q = blk >> 1, qh = q >> 1, qw = q & 1;
    int jn = tid & 63;           // n within 64-tile
    int c0 = tid >> 6;           // 0..3
    int n = nt * 64 + jn;
    const float* xg = x + (size_t)b * 1048576 +
                      (size_t)(qh * 64 + nt) * 128 + qw * 64 + jn;
    for (int cc = c0; cc < 64; cc += 4)
        xs[cc * 64 + jn] = xg[(size_t)cc * 16384];
    __syncthreads();

    int o0 = (tid >> 6) * 8;     // 8 outputs per thread per projection
    float at[8], ap[8], ag[8];
#pragma unroll
    for (int k = 0; k < 8; k++) { at[k] = tb[o0+k]; ap[k] = pb[o0+k]; ag[k] = gb[o0+k]; }
    for (int c = 0; c < 64; ++c) {
        float xv = xs[c * 64 + jn];
#pragma unroll
        for (int k = 0; k < 8; k++) {
            at[k] += tw[(o0+k)*64 + c] * xv;
            ap[k] += pw[(o0+k)*64 + c] * xv;
            ag[k] += gw[(o0+k)*64 + c] * xv;
        }
    }
#pragma unroll
    for (int k = 0; k < 8; k++) at[k] *= 1.44269504088896f;   // log2(e)

    // theta/phi: contiguous 16B per thread
    uint16_t* dT = th  + ((size_t)blk * 4096 + n) * 32 + o0;
    uint16_t* dP = phT + ((size_t)blk * 4096 + n) * 32 + o0;
#pragma unroll
    for (int k = 0; k < 8; k += 2) {
        *(uint32_t*)(dT + k) = (uint32_t)f2bf(at[k]) | ((uint32_t)f2bf(at[k+1]) << 16);
        *(uint32_t*)(dP + k) = (uint32_t)f2bf(ap[k]) | ((uint32_t)f2bf(ap[k+1]) << 16);
    }
    // g: tile-blocked [tile][o][k]
    uint16_t* dV = vP + (size_t)blk * 131072 + (size_t)nt * 2048 + o0 * 64 + jn;
#pragma unroll
    for (int k = 0; k < 8; k++) dV[k * 64] = f2bf(ag[k]);
}

// ---------------------------------------------------------------------------
// Kernel 2: fused attention. Transposed-P formulation (validated r3):
//   S^T = mfma_16x16x32(A=K, B=Q): rows=keys, cols=queries
//   P^T (exp2 + perm-pack) feeds mfma_16x16x16 B operand directly.
// K+V tiles LDS-staged per WG (double-buffered, 1 barrier/tile, reg prefetch).
// Row-sums via ones-row MFMA. 2-way split-K, plain partial stores (no atomics).
// grid: blk(8) x rowgroup(32) x kc(2) = 512 WGs of 4 waves; wave = 32 rows.
// ---------------------------------------------------------------------------
__global__ __launch_bounds__(256, 2) void flash_kernel(
    const uint16_t* __restrict__ th, const uint16_t* __restrict__ phT,
    const uint16_t* __restrict__ vP, float* __restrict__ ypart,
    float* __restrict__ lpart)
{
    __shared__ uint16_t ldsK[2][64 * 40];   // 64 keys x 40(pad) ch, 80B rows
    __shared__ uint16_t ldsV[2][32 * 72];   // 32 o x 72(pad) keys, 144B rows
    int kc  = blockIdx.x & 1;
    int rg  = (blockIdx.x >> 1) & 31;
    int blk = blockIdx.x >> 6;
    int tid = threadIdx.x, wid = tid >> 6, lane = tid & 63;
    int quad = lane >> 4, low = lane & 15;
    int n0 = rg * 128 + wid * 32;

    const uint16_t* thB = th  + (size_t)blk * 131072;
    const uint16_t* kG  = phT + (size_t)blk * 131072 + (size_t)kc * 65536;
    const uint16_t* vG  = vP  + (size_t)blk * 131072 + (size_t)kc * 65536;

    bf16x8 qf0 = *(const bf16x8*)(thB + (n0 + low) * 32 + quad * 8);
    bf16x8 qf1 = *(const bf16x8*)(thB + (n0 + 16 + low) * 32 + quad * 8);

    const int kWr = (tid >> 2) * 40 + (tid & 3) * 8;   // u16 idx, 16B-aligned
    const int vWr = (tid >> 3) * 72 + (tid & 7) * 8;
    const u32x4* kSrc = (const u32x4*)kG + tid;        // tile t: +t*256
    const u32x4* vSrc = (const u32x4*)vG + tid;

    u32x4 kreg = kSrc[0], vreg = vSrc[0];
    *(u32x4*)(&ldsK[0][kWr]) = kreg;
    *(u32x4*)(&ldsV[0][vWr]) = vreg;
    __syncthreads();

    floatx4 zero = {0.f, 0.f, 0.f, 0.f};
    floatx4 oa00 = zero, oa01 = zero, oa10 = zero, oa11 = zero;  // [qg][og]
    floatx4 os0 = zero, os1 = zero;                              // row sums
    union { uint32_t u[2]; short4v v; } ones;
    ones.u[0] = 0x3F803F80u; ones.u[1] = 0x3F803F80u;

    for (int t = 0; t < 32; ++t) {
        int buf = t & 1;
        if (t < 31) { kreg = kSrc[(t + 1) * 256]; vreg = vSrc[(t + 1) * 256]; }
        const uint16_t* Kb = ldsK[buf];
        const uint16_t* Vb = ldsV[buf];
#pragma unroll
        for (int c = 0; c < 4; ++c) {
            bf16x8  kf = *(const bf16x8*)(Kb + (c * 16 + low) * 40 + quad * 8);
            short4v v0 = *(const short4v*)(Vb + low * 72 + c * 16 + quad * 4);
            short4v v1 = *(const short4v*)(Vb + (16 + low) * 72 + c * 16 + quad * 4);
            floatx4 sa0 = __builtin_amdgcn_mfma_f32_16x16x32_bf16(kf, qf0, zero, 0, 0, 0);
            floatx4 sa1 = __builtin_amdgcn_mfma_f32_16x16x32_bf16(kf, qf1, zero, 0, 0, 0);

            union { uint32_t u[2]; short4v v; } P0, P1;
            {
                float p0 = __builtin_amdgcn_exp2f(sa0[0]);
                float p1 = __builtin_amdgcn_exp2f(sa0[1]);
                float p2 = __builtin_amdgcn_exp2f(sa0[2]);
                float p3 = __builtin_amdgcn_exp2f(sa0[3]);
                uint32_t b0 = __float_as_uint(p0) + 0x8000u;
                uint32_t b1 = __float_as_uint(p1) + 0x8000u;
                uint32_t b2 = __float_as_uint(p2) + 0x8000u;
                uint32_t b3 = __float_as_uint(p3) + 0x8000u;
                P0.u[0] = __builtin_amdgcn_perm(b1, b0, 0x07060302u);
                P0.u[1] = __builtin_amdgcn_perm(b3, b2, 0x07060302u);
            }
            {
                float p0 = __builtin_amdgcn_exp2f(sa1[0]);
                float p1 = __builtin_amdgcn_exp2f(sa1[1]);
                float p2 = __builtin_amdgcn_exp2f(sa1[2]);
                float p3 = __builtin_amdgcn_exp2f(sa1[3]);
                uint32_t b0 = __float_as_uint(p0) + 0x8000u;
                uint32_t b1 = __float_as_uint(p1) + 0x8000u;
                uint32_t b2 = __float_as_uint(p2) + 0x8000u;
                uint32_t b3 = __float_as_uint(p3) + 0x8000u;
                P1.u[0] = __builtin_amdgcn_perm(b1, b0, 0x07060302u);
                P1.u[1] = __builtin_amdgcn_perm(b3, b2, 0x07060302u);
            }
            oa00 = __builtin_amdgcn_mfma_f32_16x16x16bf16_1k(v0, P0.v, oa00, 0, 0, 0);
            oa01 = __builtin_amdgcn_mfma_f32_16x16x16bf16_1k(v1, P0.v, oa01, 0, 0, 0);
            oa10 = __builtin_amdgcn_mfma_f32_16x16x16bf16_1k(v0, P1.v, oa10, 0, 0, 0);
            oa11 = __builtin_amdgcn_mfma_f32_16x16x16bf16_1k(v1, P1.v, oa11, 0, 0, 0);
            os0  = __builtin_amdgcn_mfma_f32_16x16x16bf16_1k(ones.v, P0.v, os0, 0, 0, 0);
            os1  = __builtin_amdgcn_mfma_f32_16x16x16bf16_1k(ones.v, P1.v, os1, 0, 0, 0);
        }
        if (t < 31) {
            *(u32x4*)(&ldsK[buf ^ 1][kWr]) = kreg;
            *(u32x4*)(&ldsV[buf ^ 1][vWr]) = vreg;
        }
        __syncthreads();
    }

    float* yB = ypart + (size_t)(kc * 8 + blk) * 131072;   // [o=32][4096]
#pragma unroll
    for (int r = 0; r < 4; ++r) {
        yB[(size_t)(     quad * 4 + r) * 4096 + n0 +      low] = oa00[r];
        yB[(size_t)(16 + quad * 4 + r) * 4096 + n0 +      low] = oa01[r];
        yB[(size_t)(     quad * 4 + r) * 4096 + n0 + 16 + low] = oa10[r];
        yB[(size_t)(16 + quad * 4 + r) * 4096 + n0 + 16 + low] = oa11[r];
    }
    if (quad == 0) {
        lpart[(size_t)(kc * 8 + blk) * 4096 + n0 +      low] = os0[0];
        lpart[(size_t)(kc * 8 + blk) * 4096 + n0 + 16 + low] = os1[0];
    }
}

// ---------------------------------------------------------------------------
// Kernel 3: combine split-K + normalize + W-projection + BN partial sums.
// grid: blk(8) x chalf(2) x nt(16) = 256 WGs.
// ---------------------------------------------------------------------------
__global__ __launch_bounds__(256) void wy_kernel(
    const float* __restrict__ ypart, const float* __restrict__ lpart,
    const float* __restrict__ w_w, const float* __restrict__ w_b,
    float* __restrict__ wy, float* __restrict__ accum)
{
    int nt  = blockIdx.x & 15;
    int ch  = (blockIdx.x >> 4) & 1;
    int blk = blockIdx.x >> 5;
    int tid = threadIdx.x, lane = tid & 63;
    int n = nt * 256 + tid;
    int q = blk >> 1;

    const float* y0 = ypart + (size_t)blk * 131072 + n;
    const float* y1 = ypart + (size_t)(8 + blk) * 131072 + n;
    float rinv = 1.0f / (lpart[(size_t)blk * 4096 + n] +
                         lpart[(size_t)(8 + blk) * 4096 + n]);
    float yv[32];
#pragma unroll
    for (int o = 0; o < 32; o++) yv[o] = (y0[(size_t)o * 4096] + y1[(size_t)o * 4096]) * rinv;

    float* wB = wy + (size_t)blk * 262144 + (size_t)ch * 131072 + n;
    for (int cc = 0; cc < 32; ++cc) {
        int c = ch * 32 + cc;
        float acc = w_b[c];
#pragma unroll
        for (int o = 0; o < 32; o++) acc += w_w[c * 32 + o] * yv[o];
        wB[(size_t)cc * 4096] = acc;
        // BN partials: wave-reduce then one atomic per wave
        float s = acc, ss = acc * acc;
        for (int m = 1; m < 64; m <<= 1) { s += __shfl_xor(s, m); ss += __shfl_xor(ss, m); }
        if (lane == 0) {
            atomicAdd(&accum[(q * 64 + c) * 2],     s);
            atomicAdd(&accum[(q * 64 + c) * 2 + 1], ss);
        }
    }
}

// ---------------------------------------------------------------------------
// Kernel 4: tiny BN finisher — 1 WG, 256 threads = 4q x 64c.
// ---------------------------------------------------------------------------
__global__ __launch_bounds__(256) void stats_kernel(
    const float* __restrict__ accum, const float* __restrict__ gamma,
    const float* __restrict__ beta, float2* __restrict__ stats)
{
    int t = threadIdx.x;            // q*64+c
    int c = t & 63;
    float S  = accum[t * 2];
    float SS = accum[t * 2 + 1];
    float mu  = S * (1.0f / 8192.0f);
    float var = SS * (1.0f / 8192.0f) - mu * mu;
    float scale = gamma[c] * rsqrtf(var + 1e-5f);
    float shift = beta[c] - mu * scale;
    stats[t] = make_float2(scale, shift);
}

// ---------------------------------------------------------------------------
// Kernel 5: out = (wy * scale + shift) + x, quadrant reassembly (fp32 out).
// ---------------------------------------------------------------------------
__global__ __launch_bounds__(256) void final_kernel(
    const float* __restrict__ wy, const float2* __restrict__ stats,
    const float* __restrict__ x, float* __restrict__ out)
{
    size_t idx = (size_t)blockIdx.x * 256 + threadIdx.x;
    int n   = (int)(idx & 4095);
    int c   = (int)((idx >> 12) & 63);
    int blk = (int)(idx >> 18);
    int b = blk & 1, q = blk >> 1, qh = q >> 1, qw = q & 1;
    int i = n >> 6, j = n & 63;
    float2 sc = stats[q * 64 + c];
    float v = wy[idx] * sc.x + sc.y;
    size_t xa = ((size_t)(b * 64 + c) * 128 + (qh * 64 + i)) * 128 + qw * 64 + j;
    out[xa] = v + x[xa];
}

// ---------------------------------------------------------------------------
extern "C" void kernel_launch(void* const* d_in, const int* in_sizes, int n_in,
                              void* d_out, int out_size, void* d_ws, size_t ws_size,
                              hipStream_t stream)
{
    const float* x       = (const float*)d_in[0];
    const float* g_w     = (const float*)d_in[1];
    const float* g_b     = (const float*)d_in[2];
    const float* theta_w = (const float*)d_in[3];
    const float* theta_b = (const float*)d_in[4];
    const float* phi_w   = (const float*)d_in[5];
    const float* phi_b   = (const float*)d_in[6];
    const float* w_w     = (const float*)d_in[7];
    const float* w_b     = (const float*)d_in[8];
    const float* gamma   = (const float*)d_in[9];
    const float* beta    = (const float*)d_in[10];

    char* ws = (char*)d_ws;
    // wy (8MB) overlaps th/phT/vP (dead after flash) — written only by wy_kernel.
    float*    wy    = (float*)(ws);                       // 0 .. 8M
    uint16_t* th    = (uint16_t*)(ws);                    // 0 .. 2M
    uint16_t* phT   = (uint16_t*)(ws + (2u << 20));       // 2 .. 4M
    uint16_t* vP    = (uint16_t*)(ws + (4u << 20));       // 4 .. 6M
    float*    ypart = (float*)(ws + (8u << 20));          // 8 .. 16M
    float*    lpart = (float*)(ws + (16u << 20));         // 256 KB
    float*    accum = (float*)(ws + (16u << 20) + (1u << 18));   // 2 KB
    float2*   stats = (float2*)(ws + (16u << 20) + (1u << 18) + 4096);

    proj_kernel  <<<512,  256, 0, stream>>>(x, theta_w, theta_b, phi_w, phi_b,
                                            g_w, g_b, th, phT, vP, accum);
    flash_kernel <<<512,  256, 0, stream>>>(th, phT, vP, ypart, lpart);
    wy_kernel    <<<256,  256, 0, stream>>>(ypart, lpart, w_w, w_b, wy, accum);
    stats_kernel <<<1,    256, 0, stream>>>(accum, gamma, beta, stats);
    final_kernel <<<8192, 256, 0, stream>>>(wy, stats, x, (float*)d_out);
}

// Round 5
// 176.323 us; speedup vs baseline: 1.5943x; 1.4486x over previous
//
#include <hip/hip_runtime.h>
#include <stdint.h>

typedef __bf16 bf16x8 __attribute__((ext_vector_type(8)));
typedef short  short4v __attribute__((ext_vector_type(4)));   // 4 x bf16 bits
typedef float  floatx4 __attribute__((ext_vector_type(4)));
typedef uint32_t u32x4 __attribute__((ext_vector_type(4)));

#define DI __device__ __forceinline__

DI uint16_t f2bf(float f) {
    union { float f; uint32_t i; } v; v.f = f;
    uint32_t u = v.i;
    return (uint16_t)((u + 0x7FFFu + ((u >> 16) & 1u)) >> 16);  // RNE
}
// pack two floats to packed bf16 pair (a -> low half), round-half-up
DI uint32_t packbf2(float a, float b) {
    return __builtin_amdgcn_perm(__float_as_uint(b) + 0x8000u,
                                 __float_as_uint(a) + 0x8000u, 0x07060302u);
}

// ---------------------------------------------------------------------------
// Kernel 1: projections (fp32 inputs, validated r2-r4).
//   th [blk][4096][32] bf16 (theta, pre-scaled by log2 e)
//   phT[blk][4096][32] bf16 (phi)
//   vP [blk][tile][o=32][k=64] bf16 (g, tile-blocked)
// ---------------------------------------------------------------------------
__global__ __launch_bounds__(256) void proj_kernel(
    const float* __restrict__ x,
    const float* __restrict__ tw, const float* __restrict__ tb,
    const float* __restrict__ pw, const float* __restrict__ pb,
    const float* __restrict__ gw, const float* __restrict__ gb,
    uint16_t* __restrict__ th, uint16_t* __restrict__ phT,
    uint16_t* __restrict__ vP)
{
    int nt = blockIdx.x & 63, blk = blockIdx.x >> 6;
    int tid = threadIdx.x;

    __shared__ float xs[64 * 64];
    int b = blk & 1, q = blk >> 1, qh = q >> 1, qw = q & 1;
    int jn = tid & 63;
    int c0 = tid >> 6;
    int n = nt * 64 + jn;
    const float* xg = x + (size_t)b * 1048576 +
                      (size_t)(qh * 64 + nt) * 128 + qw * 64 + jn;
    for (int cc = c0; cc < 64; cc += 4)
        xs[cc * 64 + jn] = xg[(size_t)cc * 16384];
    __syncthreads();

    int o0 = (tid >> 6) * 8;
    float at[8], ap[8], ag[8];
#pragma unroll
    for (int k = 0; k < 8; k++) { at[k] = tb[o0+k]; ap[k] = pb[o0+k]; ag[k] = gb[o0+k]; }
    for (int c = 0; c < 64; ++c) {
        float xv = xs[c * 64 + jn];
#pragma unroll
        for (int k = 0; k < 8; k++) {
            at[k] += tw[(o0+k)*64 + c] * xv;
            ap[k] += pw[(o0+k)*64 + c] * xv;
            ag[k] += gw[(o0+k)*64 + c] * xv;
        }
    }
#pragma unroll
    for (int k = 0; k < 8; k++) at[k] *= 1.44269504088896f;   // log2(e)

    uint16_t* dT = th  + ((size_t)blk * 4096 + n) * 32 + o0;
    uint16_t* dP = phT + ((size_t)blk * 4096 + n) * 32 + o0;
#pragma unroll
    for (int k = 0; k < 8; k += 2) {
        *(uint32_t*)(dT + k) = (uint32_t)f2bf(at[k]) | ((uint32_t)f2bf(at[k+1]) << 16);
        *(uint32_t*)(dP + k) = (uint32_t)f2bf(ap[k]) | ((uint32_t)f2bf(ap[k+1]) << 16);
    }
    uint16_t* dV = vP + (size_t)blk * 131072 + (size_t)nt * 2048 + o0 * 64 + jn;
#pragma unroll
    for (int k = 0; k < 8; k++) dV[k * 64] = f2bf(ag[k]);
}

// ---------------------------------------------------------------------------
// Kernel 2: fused attention + W-projection + BN partial sums.
// Transposed-P formulation (validated r3/r4). Wave = 16 q-rows, full K sweep
// (64 tiles, LDS double-buffered). Epilogue: normalize by ones-MFMA row-sum,
// pack y->bf16 B-frags, wy = W-mfma + bias; per-WG (s,ss) partials per c.
// grid: blk(8) x rg(64) = 512 WGs of 4 waves (64 rows/WG).
// ---------------------------------------------------------------------------
__global__ __launch_bounds__(256, 2) void flash_kernel(
    const uint16_t* __restrict__ th, const uint16_t* __restrict__ phT,
    const uint16_t* __restrict__ vP, const float* __restrict__ w_w,
    const float* __restrict__ w_b, float* __restrict__ wy,
    float2* __restrict__ partials)
{
    __shared__ uint16_t ldsK[2][64 * 40];   // 64 keys x 40(pad) ch
    __shared__ uint16_t ldsV[2][32 * 72];   // 32 o x 72(pad) keys
    __shared__ float sred[4][64][2];
    int rg  = blockIdx.x & 63;
    int blk = blockIdx.x >> 6;
    int tid = threadIdx.x, wid = tid >> 6, lane = tid & 63;
    int quad = lane >> 4, low = lane & 15;
    int n0 = rg * 64 + wid * 16;

    const uint16_t* thB = th  + (size_t)blk * 131072;
    const uint16_t* kG  = phT + (size_t)blk * 131072;
    const uint16_t* vG  = vP  + (size_t)blk * 131072;

    bf16x8 qf = *(const bf16x8*)(thB + (n0 + low) * 32 + quad * 8);

    const int kWr = (tid >> 2) * 40 + (tid & 3) * 8;   // u16 idx, 16B aligned
    const int vWr = (tid >> 3) * 72 + (tid & 7) * 8;
    const u32x4* kSrc = (const u32x4*)kG + tid;        // tile t: +t*256
    const u32x4* vSrc = (const u32x4*)vG + tid;

    u32x4 kreg = kSrc[0], vreg = vSrc[0];
    *(u32x4*)(&ldsK[0][kWr]) = kreg;
    *(u32x4*)(&ldsV[0][vWr]) = vreg;
    __syncthreads();

    floatx4 zero = {0.f, 0.f, 0.f, 0.f};
    floatx4 oa0 = zero, oa1 = zero, os = zero;
    union { uint32_t u[2]; short4v v; } ones;
    ones.u[0] = 0x3F803F80u; ones.u[1] = 0x3F803F80u;

    for (int t = 0; t < 64; ++t) {
        int buf = t & 1;
        if (t < 63) { kreg = kSrc[(t + 1) * 256]; vreg = vSrc[(t + 1) * 256]; }
        const uint16_t* Kb = ldsK[buf];
        const uint16_t* Vb = ldsV[buf];
#pragma unroll
        for (int c = 0; c < 4; ++c) {
            bf16x8  kf = *(const bf16x8*)(Kb + (c * 16 + low) * 40 + quad * 8);
            short4v v0 = *(const short4v*)(Vb + low * 72 + c * 16 + quad * 4);
            short4v v1 = *(const short4v*)(Vb + (16 + low) * 72 + c * 16 + quad * 4);
            floatx4 sa = __builtin_amdgcn_mfma_f32_16x16x32_bf16(kf, qf, zero, 0, 0, 0);
            union { uint32_t u[2]; short4v v; } P;
            {
                float p0 = __builtin_amdgcn_exp2f(sa[0]);
                float p1 = __builtin_amdgcn_exp2f(sa[1]);
                float p2 = __builtin_amdgcn_exp2f(sa[2]);
                float p3 = __builtin_amdgcn_exp2f(sa[3]);
                P.u[0] = packbf2(p0, p1);
                P.u[1] = packbf2(p2, p3);
            }
            oa0 = __builtin_amdgcn_mfma_f32_16x16x16bf16_1k(v0, P.v, oa0, 0, 0, 0);
            oa1 = __builtin_amdgcn_mfma_f32_16x16x16bf16_1k(v1, P.v, oa1, 0, 0, 0);
            os  = __builtin_amdgcn_mfma_f32_16x16x16bf16_1k(ones.v, P.v, os, 0, 0, 0);
        }
        if (t < 63) {
            *(u32x4*)(&ldsK[buf ^ 1][kWr]) = kreg;
            *(u32x4*)(&ldsV[buf ^ 1][vWr]) = vreg;
        }
        __syncthreads();
    }

    // ---- epilogue: normalize, W-projection via MFMA, BN partials ----
    float rinv = 1.0f / os[0];
    union { uint32_t u[2]; short4v v; } Y0, Y1;
    Y0.u[0] = packbf2(oa0[0] * rinv, oa0[1] * rinv);
    Y0.u[1] = packbf2(oa0[2] * rinv, oa0[3] * rinv);
    Y1.u[0] = packbf2(oa1[0] * rinv, oa1[1] * rinv);
    Y1.u[1] = packbf2(oa1[2] * rinv, oa1[3] * rinv);

    float* wyB = wy + (size_t)blk * 262144;
    int n = n0 + low;
#pragma unroll
    for (int ct = 0; ct < 4; ++ct) {
        floatx4 acc;
#pragma unroll
        for (int r = 0; r < 4; ++r) acc[r] = w_b[ct * 16 + quad * 4 + r];
        floatx4 w0 = *(const floatx4*)(w_w + (ct * 16 + low) * 32 + quad * 4);
        floatx4 w1 = *(const floatx4*)(w_w + (ct * 16 + low) * 32 + 16 + quad * 4);
        union { uint32_t u[2]; short4v v; } W0, W1;
        W0.u[0] = packbf2(w0[0], w0[1]); W0.u[1] = packbf2(w0[2], w0[3]);
        W1.u[0] = packbf2(w1[0], w1[1]); W1.u[1] = packbf2(w1[2], w1[3]);
        acc = __builtin_amdgcn_mfma_f32_16x16x16bf16_1k(W0.v, Y0.v, acc, 0, 0, 0);
        acc = __builtin_amdgcn_mfma_f32_16x16x16bf16_1k(W1.v, Y1.v, acc, 0, 0, 0);
#pragma unroll
        for (int r = 0; r < 4; ++r) {
            wyB[(size_t)(ct * 16 + quad * 4 + r) * 4096 + n] = acc[r];
            float s = acc[r], ss = acc[r] * acc[r];
            s += __shfl_xor(s, 1); ss += __shfl_xor(ss, 1);
            s += __shfl_xor(s, 2); ss += __shfl_xor(ss, 2);
            s += __shfl_xor(s, 4); ss += __shfl_xor(ss, 4);
            s += __shfl_xor(s, 8); ss += __shfl_xor(ss, 8);
            if (low == 0) {
                sred[wid][ct * 16 + quad * 4 + r][0] = s;
                sred[wid][ct * 16 + quad * 4 + r][1] = ss;
            }
        }
    }
    __syncthreads();
    if (tid < 64) {
        float s  = sred[0][tid][0] + sred[1][tid][0] + sred[2][tid][0] + sred[3][tid][0];
        float ss = sred[0][tid][1] + sred[1][tid][1] + sred[2][tid][1] + sred[3][tid][1];
        partials[(size_t)blockIdx.x * 64 + tid] = make_float2(s, ss);
    }
}

// ---------------------------------------------------------------------------
// Kernel 3: BN stats — grid 4 (q), block 64 (c). Sum 128 WG-partials each.
// ---------------------------------------------------------------------------
__global__ __launch_bounds__(64) void stats_kernel(
    const float2* __restrict__ partials, const float* __restrict__ gamma,
    const float* __restrict__ beta, float2* __restrict__ stats)
{
    int q = blockIdx.x, c = threadIdx.x;
    float S = 0.f, SS = 0.f;
    for (int w = 0; w < 128; ++w) {            // b(2) x rg(64)
        int wg = (q * 2 + (w >> 6)) * 64 + (w & 63);
        float2 p = partials[(size_t)wg * 64 + c];
        S += p.x; SS += p.y;
    }
    float mu  = S * (1.0f / 8192.0f);
    float var = SS * (1.0f / 8192.0f) - mu * mu;
    float scale = gamma[c] * rsqrtf(var + 1e-5f);
    float shift = beta[c] - mu * scale;
    stats[q * 64 + c] = make_float2(scale, shift);
}

// ---------------------------------------------------------------------------
// Kernel 4: out = (wy * scale + shift) + x, float4-vectorized reassembly.
// ---------------------------------------------------------------------------
__global__ __launch_bounds__(256) void final_kernel(
    const float* __restrict__ wy, const float2* __restrict__ stats,
    const float* __restrict__ x, float* __restrict__ out)
{
    size_t base = ((size_t)blockIdx.x * 256 + threadIdx.x) * 4;
    int n   = (int)(base & 4095);
    int c   = (int)((base >> 12) & 63);
    int blk = (int)(base >> 18);
    int b = blk & 1, q = blk >> 1, qh = q >> 1, qw = q & 1;
    int i = n >> 6, j = n & 63;
    float2 sc = stats[q * 64 + c];
    floatx4 wv = *(const floatx4*)(wy + base);
    size_t xa = ((size_t)(b * 64 + c) * 128 + (qh * 64 + i)) * 128 + qw * 64 + j;
    floatx4 xv = *(const floatx4*)(x + xa);
    floatx4 ov;
#pragma unroll
    for (int k = 0; k < 4; ++k) ov[k] = wv[k] * sc.x + sc.y + xv[k];
    *(floatx4*)(out + xa) = ov;
}

// ---------------------------------------------------------------------------
extern "C" void kernel_launch(void* const* d_in, const int* in_sizes, int n_in,
                              void* d_out, int out_size, void* d_ws, size_t ws_size,
                              hipStream_t stream)
{
    const float* x       = (const float*)d_in[0];
    const float* g_w     = (const float*)d_in[1];
    const float* g_b     = (const float*)d_in[2];
    const float* theta_w = (const float*)d_in[3];
    const float* theta_b = (const float*)d_in[4];
    const float* phi_w   = (const float*)d_in[5];
    const float* phi_b   = (const float*)d_in[6];
    const float* w_w     = (const float*)d_in[7];
    const float* w_b     = (const float*)d_in[8];
    const float* gamma   = (const float*)d_in[9];
    const float* beta    = (const float*)d_in[10];

    char* ws = (char*)d_ws;
    uint16_t* th       = (uint16_t*)(ws);                 // 0 .. 2M
    uint16_t* phT      = (uint16_t*)(ws + (2u << 20));    // 2 .. 4M
    uint16_t* vP       = (uint16_t*)(ws + (4u << 20));    // 4 .. 6M
    float*    wy       = (float*)(ws + (6u << 20));       // 6 .. 14M
    float2*   partials = (float2*)(ws + (14u << 20));     // 256 KB
    float2*   stats    = (float2*)(ws + (14u << 20) + (1u << 18));

    proj_kernel  <<<512,  256, 0, stream>>>(x, theta_w, theta_b, phi_w, phi_b,
                                            g_w, g_b, th, phT, vP);
    flash_kernel <<<512,  256, 0, stream>>>(th, phT, vP, w_w, w_b, wy, partials);
    stats_kernel <<<4,    64,  0, stream>>>(partials, gamma, beta, stats);
    final_kernel <<<2048, 256, 0, stream>>>(wy, stats, x, (float*)d_out);
}